// Round 1
// baseline (246.449 us; speedup 1.0000x reference)
//
#include <hip/hip_runtime.h>
#include <math.h>

#define HW 4096
#define NCH 4
#define BLOCKS_PER_CH 16
#define TPB 256
#define KNN 5

// digamma for x >= 1 (we only call with positive integers as floats).
// Shift-up recurrence to x >= 6, then asymptotic series. ~1e-7 abs error.
__device__ __forceinline__ float digammaf_dev(float x) {
    float r = 0.f;
    while (x < 6.f) { r -= 1.f / x; x += 1.f; }
    float f = 1.f / x, f2 = f * f;
    float ps = logf(x) - 0.5f * f
             - f2 * (1.f / 12.f - f2 * (1.f / 120.f - f2 * (1.f / 252.f)));
    return ps + r;
}

// Branchless insert of d into ascending sorted 6-list (drops the max).
__device__ __forceinline__ void insert6(float (&s)[6], float d) {
    float t = d;
#pragma unroll
    for (int l = 0; l < 6; ++l) {
        float lo = fminf(s[l], t);
        t = fmaxf(s[l], t);
        s[l] = lo;
    }
}

__global__ __launch_bounds__(TPB) void knnmi_rows(const float* __restrict__ x,
                                                  const float* __restrict__ y,
                                                  float* __restrict__ ws) {
    __shared__ float sx[HW];
    __shared__ float sy[HW];
    __shared__ float red[TPB];

    const int c  = blockIdx.x / BLOCKS_PER_CH;   // channel 0..3
    const int rb = blockIdx.x % BLOCKS_PER_CH;   // row-block within channel

    const float* xc = x + c * HW;
    const float* yc = y + c * HW;

    // Cooperative staging: 4096 floats each via float4 (16 B/lane).
    for (int i = threadIdx.x; i < HW / 4; i += TPB) {
        ((float4*)sx)[i] = ((const float4*)xc)[i];
        ((float4*)sy)[i] = ((const float4*)yc)[i];
    }
    __syncthreads();

    const int row = rb * TPB + threadIdx.x;      // this thread's point i
    const float xi = sx[row];
    const float yi = sy[row];

    // Pass 1: 6 smallest joint (Chebyshev) distances. Two independent
    // lists (even/odd j) for ILP; merged afterwards.
    float a[6], b[6];
#pragma unroll
    for (int l = 0; l < 6; ++l) { a[l] = 3.4e38f; b[l] = 3.4e38f; }

    for (int j = 0; j < HW; j += 2) {
        float d0 = fmaxf(fabsf(xi - sx[j]),     fabsf(yi - sy[j]));
        float d1 = fmaxf(fabsf(xi - sx[j + 1]), fabsf(yi - sy[j + 1]));
        insert6(a, d0);
        insert6(b, d1);
    }
#pragma unroll
    for (int l = 0; l < 6; ++l) insert6(a, b[l]);

    const float eps = a[5];   // (k+1)-th smallest, k=5, self included

    // Pass 2: strict-< marginal counts (self counts too, matching ref).
    int nx0 = 0, nx1 = 0, ny0 = 0, ny1 = 0;
    for (int j = 0; j < HW; j += 2) {
        nx0 += (fabsf(xi - sx[j])     < eps);
        ny0 += (fabsf(yi - sy[j])     < eps);
        nx1 += (fabsf(xi - sx[j + 1]) < eps);
        ny1 += (fabsf(yi - sy[j + 1]) < eps);
    }

    float v = digammaf_dev((float)(nx0 + nx1)) + digammaf_dev((float)(ny0 + ny1));

    // Block tree-reduce 256 -> 1.
    red[threadIdx.x] = v;
    __syncthreads();
    for (int s = TPB / 2; s > 0; s >>= 1) {
        if (threadIdx.x < s) red[threadIdx.x] += red[threadIdx.x + s];
        __syncthreads();
    }
    if (threadIdx.x == 0) ws[blockIdx.x] = red[0];
}

__global__ void knnmi_final(const float* __restrict__ ws, float* __restrict__ out) {
    int c = threadIdx.x;
    if (c < NCH) {
        float s = 0.f;
        for (int i = 0; i < BLOCKS_PER_CH; ++i) s += ws[c * BLOCKS_PER_CH + i];
        float mi = digammaf_dev((float)KNN) + digammaf_dev((float)HW) - s / (float)HW;
        out[c] = fmaxf(mi, 0.f);
    }
}

extern "C" void kernel_launch(void* const* d_in, const int* in_sizes, int n_in,
                              void* d_out, int out_size, void* d_ws, size_t ws_size,
                              hipStream_t stream) {
    const float* x = (const float*)d_in[0];
    const float* y = (const float*)d_in[1];
    float* out = (float*)d_out;
    float* ws  = (float*)d_ws;   // 64 floats, fully rewritten every call

    knnmi_rows<<<NCH * BLOCKS_PER_CH, TPB, 0, stream>>>(x, y, ws);
    knnmi_final<<<1, 64, 0, stream>>>(ws, out);
}

// Round 2
// 38.809 us; speedup vs baseline: 6.3503x; 6.3503x over previous
//
#include <hip/hip_runtime.h>
#include <math.h>

#define HW 4096
#define NCH 4
#define G 16                 // lanes per row
#define ROWS_PER_BLOCK 16
#define TPB 256
#define BLOCKS_PER_CH (HW / ROWS_PER_BLOCK)   // 256
#define NBLOCKS (NCH * BLOCKS_PER_CH)         // 1024
#define KNN 5

// digamma for x >= 1 (positive integers as floats).
// Shift-up recurrence to x >= 6, then asymptotic series. ~1e-7 abs error.
__device__ __forceinline__ float digammaf_dev(float x) {
    float r = 0.f;
    while (x < 6.f) { r -= 1.f / x; x += 1.f; }
    float f = 1.f / x, f2 = f * f;
    float ps = logf(x) - 0.5f * f
             - f2 * (1.f / 12.f - f2 * (1.f / 120.f - f2 * (1.f / 252.f)));
    return ps + r;
}

// Insert d into ascending sorted 6-list (drop the max).
// med3 identity: s0' = min(s0,d); si' = med3(s[i-1], s[i], d).
// 6 independent ops (v_med3_f32), no serial chain.
__device__ __forceinline__ void insert6(float (&s)[6], float d) {
    float n0 = fminf(s[0], d);
    float n1 = __builtin_amdgcn_fmed3f(s[0], s[1], d);
    float n2 = __builtin_amdgcn_fmed3f(s[1], s[2], d);
    float n3 = __builtin_amdgcn_fmed3f(s[2], s[3], d);
    float n4 = __builtin_amdgcn_fmed3f(s[3], s[4], d);
    float n5 = __builtin_amdgcn_fmed3f(s[4], s[5], d);
    s[0] = n0; s[1] = n1; s[2] = n2; s[3] = n3; s[4] = n4; s[5] = n5;
}

__global__ __launch_bounds__(TPB) void knnmi_rows(const float* __restrict__ x,
                                                  const float* __restrict__ y,
                                                  float* __restrict__ ws) {
    __shared__ float2 sxy[HW];                 // interleaved {x,y}: 32 KB
    __shared__ float red[ROWS_PER_BLOCK];

    const int c  = blockIdx.x / BLOCKS_PER_CH;   // channel 0..3
    const int rb = blockIdx.x % BLOCKS_PER_CH;   // row-block within channel

    const float* xc = x + c * HW;
    const float* yc = y + c * HW;

    // Stage interleaved via float4 reads + 2x ds_write_b128 per iter.
    for (int i = threadIdx.x; i < HW / 4; i += TPB) {
        float4 xv = ((const float4*)xc)[i];
        float4 yv = ((const float4*)yc)[i];
        float4 p0 = make_float4(xv.x, yv.x, xv.y, yv.y);
        float4 p1 = make_float4(xv.z, yv.z, xv.w, yv.w);
        ((float4*)sxy)[2 * i]     = p0;
        ((float4*)sxy)[2 * i + 1] = p1;
    }
    __syncthreads();

    const int l   = threadIdx.x & (G - 1);       // lane within row-group
    const int r   = threadIdx.x / G;             // row within block
    const int row = rb * ROWS_PER_BLOCK + r;

    const float xi = sxy[row].x;
    const float yi = sxy[row].y;

    // Pass 1: each lane scans j = it*G + l (strided -> conflict-free b64).
    float s[6];
#pragma unroll
    for (int q = 0; q < 6; ++q) s[q] = 3.4e38f;

#pragma unroll 4
    for (int it = 0; it < HW / G; ++it) {
        float2 p = sxy[it * G + l];
        float d = fmaxf(fabsf(xi - p.x), fabsf(yi - p.y));
        insert6(s, d);
    }

    // Butterfly merge of the 16 per-lane sorted 6-lists.
#pragma unroll
    for (int m = 1; m < G; m <<= 1) {
        float o[6];
#pragma unroll
        for (int q = 0; q < 6; ++q) o[q] = __shfl_xor(s[q], m);
#pragma unroll
        for (int q = 0; q < 6; ++q) insert6(s, o[q]);
    }
    const float eps = s[5];   // (k+1)-th smallest joint distance, self included

    // Pass 2: strict-< marginal counts, split across the same lanes.
    int nx = 0, ny = 0;
#pragma unroll 4
    for (int it = 0; it < HW / G; ++it) {
        float2 p = sxy[it * G + l];
        nx += (fabsf(xi - p.x) < eps);
        ny += (fabsf(yi - p.y) < eps);
    }
    int packed = (nx << 16) | ny;                 // each sum <= 4096, no carry
#pragma unroll
    for (int m = 1; m < G; m <<= 1) packed += __shfl_xor(packed, m);
    nx = packed >> 16;
    ny = packed & 0xffff;

    if (l == 0)
        red[r] = digammaf_dev((float)nx) + digammaf_dev((float)ny);
    __syncthreads();

    if (threadIdx.x == 0) {
        float v = 0.f;
#pragma unroll
        for (int q = 0; q < ROWS_PER_BLOCK; ++q) v += red[q];
        ws[blockIdx.x] = v;
    }
}

__global__ void knnmi_final(const float* __restrict__ ws, float* __restrict__ out) {
    const int w    = threadIdx.x >> 6;    // wave = channel
    const int lane = threadIdx.x & 63;
    float sum = 0.f;
    for (int i = lane; i < BLOCKS_PER_CH; i += 64) sum += ws[w * BLOCKS_PER_CH + i];
#pragma unroll
    for (int m = 32; m; m >>= 1) sum += __shfl_xor(sum, m);
    if (lane == 0) {
        float mi = digammaf_dev((float)KNN) + digammaf_dev((float)HW)
                 - sum / (float)HW;
        out[w] = fmaxf(mi, 0.f);
    }
}

extern "C" void kernel_launch(void* const* d_in, const int* in_sizes, int n_in,
                              void* d_out, int out_size, void* d_ws, size_t ws_size,
                              hipStream_t stream) {
    const float* x = (const float*)d_in[0];
    const float* y = (const float*)d_in[1];
    float* out = (float*)d_out;
    float* ws  = (float*)d_ws;   // NBLOCKS floats, fully rewritten every call

    knnmi_rows<<<NBLOCKS, TPB, 0, stream>>>(x, y, ws);
    knnmi_final<<<1, NCH * 64, 0, stream>>>(ws, out);
}